// Round 3
// baseline (88.334 us; speedup 1.0000x reference)
//
#include <hip/hip_runtime.h>
#include <cmath>

// Radon backprojection, two-phase (no atomics).
//   Phase 1: grid (nn/256) x ACHUNKS; each block accumulates ~A/ACHUNKS
//            angles for 4 batches in registers, plain-stores partials to ws.
//   Phase 2: out[b*nn+pix] = sum_c ws[(c*B + b)*nn + pix].
// R2 post-mortem: 2M fp32 atomicAdds (~1/cyc/L2-channel) were ~30 us of the
// ~40 us kernel. Partial-write + reduce removes the serialization.

template <int BATCH>
__global__ __launch_bounds__(256) void radon_partial_kernel(
    const float* __restrict__ sino,
    const float* __restrict__ thetas,
    const float* __restrict__ positions,
    float* __restrict__ part,          // [ACHUNKS][BATCH][nn]
    int A, int P, int N, int chunk)
{
    __shared__ float s_cs[256];        // cos*inv_dp
    __shared__ float s_sn[256];        // sin*inv_dp
    const int tid = threadIdx.x;
    const float p0     = positions[0];
    const float inv_dp = 1.0f / (positions[1] - p0);
    if (tid < A) {
        float th = thetas[tid];
        s_cs[tid] = cosf(th) * inv_dp;
        s_sn[tid] = sinf(th) * inv_dp;
    }
    __syncthreads();

    const int nn  = N * N;
    const int pix = blockIdx.x * blockDim.x + tid;
    if (pix >= nn) return;

    const int a0 = blockIdx.y * chunk;
    const int a1 = min(A, a0 + chunk);

    const int x = pix % N;
    const int y = pix / N;
    const float half = (float)(N - 1) * 0.5f;
    const float cx = (float)x - half;
    const float cy = half - (float)y;
    const float q0 = -p0 * inv_dp;     // f = cx*csc + cy*snc + q0

    const int bstride = A * P;

    float acc[BATCH];
#pragma unroll
    for (int b = 0; b < BATCH; ++b) acc[b] = 0.0f;

    for (int a = a0; a < a1; ++a) {
        float f   = fmaf(cx, s_cs[a], fmaf(cy, s_sn[a], q0));
        float i0f = floorf(f);
        int   i0  = (int)i0f;
        float w   = f - i0f;
        if (i0 >= 0 && i0 <= P - 2) {
            const float* row = sino + a * P + i0;
#pragma unroll
            for (int b = 0; b < BATCH; ++b) {
                float v0 = row[(size_t)b * bstride];
                float v1 = row[(size_t)b * bstride + 1];
                acc[b] = fmaf(w, v1 - v0, acc[b] + v0);   // v0 + w*(v1-v0)
            }
        }
    }

    float* pp = part + ((size_t)blockIdx.y * BATCH) * nn + pix;
#pragma unroll
    for (int b = 0; b < BATCH; ++b) pp[(size_t)b * nn] = acc[b];
}

__global__ __launch_bounds__(256) void radon_reduce_kernel(
    const float* __restrict__ part,    // [nchunks][BN] where BN = BATCH*nn
    float* __restrict__ out,
    int BN, int nchunks)
{
    int i = blockIdx.x * blockDim.x + threadIdx.x;
    if (i >= BN) return;
    float s = 0.0f;
    for (int c = 0; c < nchunks; ++c)
        s += part[(size_t)c * BN + i];
    out[i] = s;
}

// Fallback (shouldn't trigger for the real shape): direct atomic version.
__global__ __launch_bounds__(256) void radon_atomic_kernel(
    const float* __restrict__ sino,
    const float* __restrict__ thetas,
    const float* __restrict__ positions,
    float* __restrict__ out,
    int A, int P, int N, int BC)
{
    const int nn  = N * N;
    const int pix = blockIdx.x * blockDim.x + threadIdx.x;
    if (pix >= nn) return;
    const float p0     = positions[0];
    const float inv_dp = 1.0f / (positions[1] - p0);
    const int x = pix % N;
    const int y = pix / N;
    const float half = (float)(N - 1) * 0.5f;
    const float cx = (float)x - half;
    const float cy = half - (float)y;
    for (int b = 0; b < BC; ++b) {
        float acc = 0.0f;
        for (int a = 0; a < A; ++a) {
            float th = thetas[a];
            float f  = (cx * cosf(th) + cy * sinf(th) - p0) * inv_dp;
            float i0f = floorf(f);
            int i0 = (int)i0f;
            float w = f - i0f;
            if (i0 >= 0 && i0 <= P - 2) {
                const float* row = sino + ((size_t)b * A + a) * P + i0;
                acc = fmaf(w, row[1] - row[0], acc + row[0]);
            }
        }
        out[(size_t)b * nn + pix] = acc;
    }
}

extern "C" void kernel_launch(void* const* d_in, const int* in_sizes, int n_in,
                              void* d_out, int out_size, void* d_ws, size_t ws_size,
                              hipStream_t stream) {
    const float* sino      = (const float*)d_in[0];
    const float* thetas    = (const float*)d_in[1];
    const float* positions = (const float*)d_in[2];
    float* out             = (float*)d_out;

    const int A  = in_sizes[1];               // 180
    const int P  = in_sizes[2];               // 384
    const int BC = in_sizes[0] / (A * P);     // B*C = 4
    const int N  = (int)lroundf(sqrtf((float)(out_size / BC)));
    const int nn = N * N;

    const int ACHUNKS = 8;                    // 2048 blocks -> full occupancy
    const int chunk   = (A + ACHUNKS - 1) / ACHUNKS;
    const size_t need = (size_t)ACHUNKS * BC * nn * sizeof(float);

    if (BC == 4 && A <= 256 && ws_size >= need) {
        float* part = (float*)d_ws;
        dim3 block(256);
        dim3 grid1((nn + 255) / 256, ACHUNKS);
        radon_partial_kernel<4><<<grid1, block, 0, stream>>>(
            sino, thetas, positions, part, A, P, N, chunk);
        const int BN = BC * nn;
        dim3 grid2((BN + 255) / 256);
        radon_reduce_kernel<<<grid2, block, 0, stream>>>(part, out, BN, ACHUNKS);
    } else {
        dim3 block(256);
        dim3 grid((nn + 255) / 256);
        radon_atomic_kernel<<<grid, block, 0, stream>>>(
            sino, thetas, positions, out, A, P, N, BC);
    }
}

// Round 4
// 87.498 us; speedup vs baseline: 1.0096x; 1.0096x over previous
//
#include <hip/hip_runtime.h>
#include <cmath>

// Radon backprojection, two-phase, BRANCHLESS gather loop.
// R3 post-mortem: atomics were not the bottleneck; the valid-branch around
// the gather loads blocked cross-iteration load pipelining -> ~300 cyc
// latency exposed per angle. Fix per the reference: clamp i0 to [0,P-2],
// always load (in-bounds), multiply contribution by valid mask. Branchless
// body lets the compiler keep many loads in flight.

template <int BATCH>
__global__ __launch_bounds__(256) void radon_partial_kernel(
    const float* __restrict__ sino,
    const float* __restrict__ thetas,
    const float* __restrict__ positions,
    float* __restrict__ part,          // [ACHUNKS][BATCH][nn]
    int A, int P, int N, int chunk)
{
    __shared__ float s_cs[256];        // cos*inv_dp
    __shared__ float s_sn[256];        // sin*inv_dp
    const int tid = threadIdx.x;
    const float p0     = positions[0];
    const float inv_dp = 1.0f / (positions[1] - p0);
    if (tid < A) {
        float th = thetas[tid];
        s_cs[tid] = cosf(th) * inv_dp;
        s_sn[tid] = sinf(th) * inv_dp;
    }
    __syncthreads();

    const int nn  = N * N;
    const int pix = blockIdx.x * blockDim.x + tid;
    if (pix >= nn) return;

    const int a0 = blockIdx.y * chunk;
    const int a1 = min(A, a0 + chunk);

    const int x = pix % N;
    const int y = pix / N;
    const float half = (float)(N - 1) * 0.5f;
    const float cx = (float)x - half;
    const float cy = half - (float)y;
    const float q0 = -p0 * inv_dp;     // f = cx*cs + cy*sn + q0

    const int bstride = A * P;
    const float* sb0 = sino;
    const float* sb1 = sino + (size_t)1 * bstride;
    const float* sb2 = sino + (size_t)2 * bstride;
    const float* sb3 = sino + (size_t)3 * bstride;

    float acc[BATCH];
#pragma unroll
    for (int b = 0; b < BATCH; ++b) acc[b] = 0.0f;

#pragma unroll 2
    for (int a = a0; a < a1; ++a) {
        float f   = fmaf(cx, s_cs[a], fmaf(cy, s_sn[a], q0));
        float i0f = floorf(f);
        int   i0  = (int)i0f;
        float w   = f - i0f;
        // valid mask as float; clamp index so loads are always in-bounds
        float m   = (i0 >= 0 && i0 <= P - 2) ? 1.0f : 0.0f;
        int   ic  = min(max(i0, 0), P - 2);
        int   off = a * P + ic;

        if (BATCH == 4) {
            float v00 = sb0[off], v01 = sb0[off + 1];
            float v10 = sb1[off], v11 = sb1[off + 1];
            float v20 = sb2[off], v21 = sb2[off + 1];
            float v30 = sb3[off], v31 = sb3[off + 1];
            acc[0] = fmaf(m, fmaf(w, v01 - v00, v00), acc[0]);
            acc[1] = fmaf(m, fmaf(w, v11 - v10, v10), acc[1]);
            acc[2] = fmaf(m, fmaf(w, v21 - v20, v20), acc[2]);
            acc[3] = fmaf(m, fmaf(w, v31 - v30, v30), acc[3]);
        } else {
#pragma unroll
            for (int b = 0; b < BATCH; ++b) {
                float v0 = sino[(size_t)b * bstride + off];
                float v1 = sino[(size_t)b * bstride + off + 1];
                acc[b] = fmaf(m, fmaf(w, v1 - v0, v0), acc[b]);
            }
        }
    }

    float* pp = part + ((size_t)blockIdx.y * BATCH) * nn + pix;
#pragma unroll
    for (int b = 0; b < BATCH; ++b) pp[(size_t)b * nn] = acc[b];
}

__global__ __launch_bounds__(256) void radon_reduce_kernel(
    const float4* __restrict__ part,   // [nchunks][BN4] in float4
    float4* __restrict__ out,
    int BN4, int nchunks)
{
    int i = blockIdx.x * blockDim.x + threadIdx.x;
    if (i >= BN4) return;
    float4 s = make_float4(0.f, 0.f, 0.f, 0.f);
    for (int c = 0; c < nchunks; ++c) {
        float4 v = part[(size_t)c * BN4 + i];
        s.x += v.x; s.y += v.y; s.z += v.z; s.w += v.w;
    }
    out[i] = s;
}

// Generic fallback: direct per-batch kernel (no atomics needed).
__global__ __launch_bounds__(256) void radon_direct_kernel(
    const float* __restrict__ sino,
    const float* __restrict__ thetas,
    const float* __restrict__ positions,
    float* __restrict__ out,
    int A, int P, int N, int BC)
{
    const int nn  = N * N;
    const int pix = blockIdx.x * blockDim.x + threadIdx.x;
    if (pix >= nn) return;
    const float p0     = positions[0];
    const float inv_dp = 1.0f / (positions[1] - p0);
    const int x = pix % N;
    const int y = pix / N;
    const float half = (float)(N - 1) * 0.5f;
    const float cx = (float)x - half;
    const float cy = half - (float)y;
    for (int b = 0; b < BC; ++b) {
        float acc = 0.0f;
        for (int a = 0; a < A; ++a) {
            float th = thetas[a];
            float f  = (cx * cosf(th) + cy * sinf(th) - p0) * inv_dp;
            float i0f = floorf(f);
            int i0 = (int)i0f;
            float w = f - i0f;
            float m = (i0 >= 0 && i0 <= P - 2) ? 1.0f : 0.0f;
            int ic = min(max(i0, 0), P - 2);
            const float* row = sino + ((size_t)b * A + a) * P + ic;
            acc = fmaf(m, fmaf(w, row[1] - row[0], row[0]), acc);
        }
        out[(size_t)b * nn + pix] = acc;
    }
}

extern "C" void kernel_launch(void* const* d_in, const int* in_sizes, int n_in,
                              void* d_out, int out_size, void* d_ws, size_t ws_size,
                              hipStream_t stream) {
    const float* sino      = (const float*)d_in[0];
    const float* thetas    = (const float*)d_in[1];
    const float* positions = (const float*)d_in[2];
    float* out             = (float*)d_out;

    const int A  = in_sizes[1];               // 180
    const int P  = in_sizes[2];               // 384
    const int BC = in_sizes[0] / (A * P);     // B*C = 4
    const int N  = (int)lroundf(sqrtf((float)(out_size / BC)));
    const int nn = N * N;

    const int ACHUNKS = 8;                    // 2048 blocks -> 32 waves/CU
    const int chunk   = (A + ACHUNKS - 1) / ACHUNKS;
    const size_t need = (size_t)ACHUNKS * BC * nn * sizeof(float);

    if (BC == 4 && A <= 256 && ws_size >= need && (nn % 4) == 0) {
        float* part = (float*)d_ws;
        dim3 block(256);
        dim3 grid1((nn + 255) / 256, ACHUNKS);
        radon_partial_kernel<4><<<grid1, block, 0, stream>>>(
            sino, thetas, positions, part, A, P, N, chunk);
        const int BN4 = BC * nn / 4;
        dim3 grid2((BN4 + 255) / 256);
        radon_reduce_kernel<<<grid2, block, 0, stream>>>(
            (const float4*)part, (float4*)out, BN4, ACHUNKS);
    } else {
        dim3 block(256);
        dim3 grid((nn + 255) / 256);
        radon_direct_kernel<<<grid, block, 0, stream>>>(
            sino, thetas, positions, out, A, P, N, BC);
    }
}

// Round 5
// 83.974 us; speedup vs baseline: 1.0519x; 1.0420x over previous
//
#include <hip/hip_runtime.h>
#include <cmath>

// Radon backprojection, two-phase, LDS-staged gather.
// R4 post-mortem: gather kernel is vmem-pipe bound (~16 cyc per scattered
// dword gather instr; 8 instrs/thread-angle). Fix: stage the 4 batch rows of
// the current angle into LDS (coalesced float2 copies, double-buffered) and
// gather from LDS (ds_read2_b32, ~6 cyc, conflict-free for stride<=1).

template <int BATCH>
__global__ __launch_bounds__(256) void radon_partial_lds(
    const float* __restrict__ sino,
    const float* __restrict__ thetas,
    const float* __restrict__ positions,
    float* __restrict__ part,          // [ACHUNKS][BATCH][nn]
    int A, int P, int N, int chunk)
{
    constexpr int MAXP = 512;
    __shared__ float s_cs[256];        // cos*inv_dp
    __shared__ float s_sn[256];        // sin*inv_dp
    __shared__ float buf[2][BATCH * MAXP];   // [dbuf][batch*P] compact rows

    const int tid = threadIdx.x;
    const float p0     = positions[0];
    const float inv_dp = 1.0f / (positions[1] - p0);
    if (tid < A) {
        float th = thetas[tid];
        s_cs[tid] = cosf(th) * inv_dp;
        s_sn[tid] = sinf(th) * inv_dp;
    }

    const int nn    = N * N;
    const int pix   = blockIdx.x * blockDim.x + tid;
    const int a0    = blockIdx.y * chunk;
    const int cnt   = min(A, a0 + chunk) - a0;
    const int bstride = A * P;
    const int halfP = P >> 1;

    const int x = pix % N;
    const int y = pix / N;
    const float half = (float)(N - 1) * 0.5f;
    const float cx = (float)x - half;
    const float cy = half - (float)y;
    const float q0 = -p0 * inv_dp;     // f = cx*cs + cy*sn + q0

    float acc[BATCH];
#pragma unroll
    for (int b = 0; b < BATCH; ++b) acc[b] = 0.0f;

    // Stage first angle into buf[0] (coalesced float2, 3 full waves active).
    if (tid < halfP) {
#pragma unroll
        for (int b = 0; b < BATCH; ++b) {
            float2 v = *(const float2*)(sino + (size_t)b * bstride
                                             + (size_t)a0 * P + 2 * tid);
            *(float2*)(&buf[0][b * P + 2 * tid]) = v;
        }
    }
    __syncthreads();                   // also covers s_cs/s_sn

    for (int i = 0; i < cnt; ++i) {
        const int cur = i & 1;
        // Prefetch next angle's rows into the other buffer.
        if (i + 1 < cnt && tid < halfP) {
            const int an = a0 + i + 1;
#pragma unroll
            for (int b = 0; b < BATCH; ++b) {
                float2 v = *(const float2*)(sino + (size_t)b * bstride
                                                 + (size_t)an * P + 2 * tid);
                *(float2*)(&buf[cur ^ 1][b * P + 2 * tid]) = v;
            }
        }

        const int a = a0 + i;
        float f   = fmaf(cx, s_cs[a], fmaf(cy, s_sn[a], q0));
        float i0f = floorf(f);
        int   i0  = (int)i0f;
        float w   = f - i0f;
        float m   = (i0 >= 0 && i0 <= P - 2) ? 1.0f : 0.0f;
        int   ic  = min(max(i0, 0), P - 2);
        const float* bp = &buf[cur][ic];
#pragma unroll
        for (int b = 0; b < BATCH; ++b) {
            float v0 = bp[b * P];      // ds_read2_b32 candidates
            float v1 = bp[b * P + 1];
            acc[b] = fmaf(m, fmaf(w, v1 - v0, v0), acc[b]);
        }
        __syncthreads();               // staging done; buf[cur] reads done
    }

    if (pix < nn) {
        float* pp = part + ((size_t)blockIdx.y * BATCH) * nn + pix;
#pragma unroll
        for (int b = 0; b < BATCH; ++b) pp[(size_t)b * nn] = acc[b];
    }
}

__global__ __launch_bounds__(256) void radon_reduce_kernel(
    const float4* __restrict__ part,   // [nchunks][BN4] in float4
    float4* __restrict__ out,
    int BN4, int nchunks)
{
    int i = blockIdx.x * blockDim.x + threadIdx.x;
    if (i >= BN4) return;
    float4 s = make_float4(0.f, 0.f, 0.f, 0.f);
    for (int c = 0; c < nchunks; ++c) {
        float4 v = part[(size_t)c * BN4 + i];
        s.x += v.x; s.y += v.y; s.z += v.z; s.w += v.w;
    }
    out[i] = s;
}

// Generic fallback: direct per-batch kernel.
__global__ __launch_bounds__(256) void radon_direct_kernel(
    const float* __restrict__ sino,
    const float* __restrict__ thetas,
    const float* __restrict__ positions,
    float* __restrict__ out,
    int A, int P, int N, int BC)
{
    const int nn  = N * N;
    const int pix = blockIdx.x * blockDim.x + threadIdx.x;
    if (pix >= nn) return;
    const float p0     = positions[0];
    const float inv_dp = 1.0f / (positions[1] - p0);
    const int x = pix % N;
    const int y = pix / N;
    const float half = (float)(N - 1) * 0.5f;
    const float cx = (float)x - half;
    const float cy = half - (float)y;
    for (int b = 0; b < BC; ++b) {
        float acc = 0.0f;
        for (int a = 0; a < A; ++a) {
            float th = thetas[a];
            float f  = (cx * cosf(th) + cy * sinf(th) - p0) * inv_dp;
            float i0f = floorf(f);
            int i0 = (int)i0f;
            float w = f - i0f;
            float m = (i0 >= 0 && i0 <= P - 2) ? 1.0f : 0.0f;
            int ic = min(max(i0, 0), P - 2);
            const float* row = sino + ((size_t)b * A + a) * P + ic;
            acc = fmaf(m, fmaf(w, row[1] - row[0], row[0]), acc);
        }
        out[(size_t)b * nn + pix] = acc;
    }
}

extern "C" void kernel_launch(void* const* d_in, const int* in_sizes, int n_in,
                              void* d_out, int out_size, void* d_ws, size_t ws_size,
                              hipStream_t stream) {
    const float* sino      = (const float*)d_in[0];
    const float* thetas    = (const float*)d_in[1];
    const float* positions = (const float*)d_in[2];
    float* out             = (float*)d_out;

    const int A  = in_sizes[1];               // 180
    const int P  = in_sizes[2];               // 384
    const int BC = in_sizes[0] / (A * P);     // B*C = 4
    const int N  = (int)lroundf(sqrtf((float)(out_size / BC)));
    const int nn = N * N;

    const int ACHUNKS = 8;                    // 2048 blocks -> 32 waves/CU
    const int chunk   = (A + ACHUNKS - 1) / ACHUNKS;
    const size_t need = (size_t)ACHUNKS * BC * nn * sizeof(float);

    const bool fast = (BC == 4) && (A <= 256) && (P <= 512) && ((P & 1) == 0)
                   && (ws_size >= need) && ((nn & 255) == 0) && ((nn & 3) == 0);

    if (fast) {
        float* part = (float*)d_ws;
        dim3 block(256);
        dim3 grid1(nn / 256, ACHUNKS);
        radon_partial_lds<4><<<grid1, block, 0, stream>>>(
            sino, thetas, positions, part, A, P, N, chunk);
        const int BN4 = BC * nn / 4;
        dim3 grid2((BN4 + 255) / 256);
        radon_reduce_kernel<<<grid2, block, 0, stream>>>(
            (const float4*)part, (float4*)out, BN4, ACHUNKS);
    } else {
        dim3 block(256);
        dim3 grid((nn + 255) / 256);
        radon_direct_kernel<<<grid, block, 0, stream>>>(
            sino, thetas, positions, out, A, P, N, BC);
    }
}